// Round 7
// baseline (364.464 us; speedup 1.0000x reference)
//
#include <hip/hip_runtime.h>
#include <hip/hip_bf16.h>

// DIN attention unit, MI355X — round 13: compute each layer ONCE.
// R6-R12 invariant: ~65us/pass regardless of weight path, occupancy,
// NPOS, or load coalescing (R12's LDS staging made it WORSE, 67->83us).
// VALUBusy*dur ~= 38us/pass => instruction-stream-bound: the layer-1
// tower (672 FMA/pos) was recomputed in ALL THREE passes (~3600 ops/pos
// total). Fix: cache activations between passes in bf16 (absmax threshold
// 3.0; bf16 costs ~1e-2):
//   passA: keys -> h0 (pre-act needs NO stats), stats0, write h0 bf16
//   passB: h0 -> dice0 -> h1(+b1)=v1, stats1, write v1 bf16
//   passC: keys+v1 -> dice1 -> score -> weighted key sum
// ~1780 ops/pos total (2x less). Needs 102MB workspace: runtime-checked;
// template<CACHED=false> falls back to R11's proven recompute kernels.
// Weights stay on scalar path; AGENT-scope stat readback (R9 fix).
// mask input UNUSED (reference uses unmasked scores — reproduced bug).

#define BB 512
#define TT 2048
#define DD 20
#define C0 32
#define C1 16

#define NTH 256              // 4 waves/block
#define CHUNK 512            // rows per block
#define NPART (TT / CHUNK)   // 4 blocks per batch
#define GRID (BB * NPART)    // 2048 blocks
#define NSLOT 8              // atomic slot-split

// ws float offsets
#define WS_P1 0              // 8 slots * (32 sum + 32 sq)
#define WS_P2 512            // 8 slots * (16 sum + 16 sq)
#define WS_ZERO_N 768
#define WS_BLOB 896
#define BLOB_J 24            // 20 wM + c + pad
#define BLOB_B (C0 * BLOB_J)
// byte offsets for the bf16 activation caches
#define H0_OFFB ((size_t)(WS_BLOB + BB * BLOB_B) * 4)      // 1,576,448
#define H0_BYTES ((size_t)BB * TT * C0 * 2)                // 67,108,864
#define H1_OFFB (H0_OFFB + H0_BYTES)
#define H1_BYTES ((size_t)BB * TT * C1 * 2)                // 33,554,432
#define WS_NEED (H1_OFFB + H1_BYTES)

#define PIN(x) asm volatile("" : "+v"(x))
#define AGLOAD(p) \
    __hip_atomic_load((p), __ATOMIC_RELAXED, __HIP_MEMORY_SCOPE_AGENT)

__device__ __forceinline__ float fast_sigmoid(float x) {
    return __builtin_amdgcn_rcpf(1.0f + __expf(-x));
}

__device__ __forceinline__ void load_krow(const float* __restrict__ row,
                                          float* kk) {
    const float4* kr = (const float4*)row;  // rows are 80B => 16B aligned
    float4 a = kr[0], b = kr[1], c = kr[2], d = kr[3], e = kr[4];
    kk[0] = a.x; kk[1] = a.y; kk[2] = a.z; kk[3] = a.w;
    kk[4] = b.x; kk[5] = b.y; kk[6] = b.z; kk[7] = b.w;
    kk[8] = c.x; kk[9] = c.y; kk[10] = c.z; kk[11] = c.w;
    kk[12] = d.x; kk[13] = d.y; kk[14] = d.z; kk[15] = d.w;
    kk[16] = e.x; kk[17] = e.y; kk[18] = e.z; kk[19] = e.w;
}

// bf16 pack/unpack. Scalar casts -> compiler fuses to v_cvt_pk_bf16_f32.
__device__ __forceinline__ unsigned int pkbf(float a, float b) {
    union { __hip_bfloat16 h[2]; unsigned int u; } cv;
    cv.h[0] = __float2bfloat16(a);
    cv.h[1] = __float2bfloat16(b);
    return cv.u;
}
__device__ __forceinline__ float bflo(unsigned int u) {
    return __uint_as_float(u << 16);
}
__device__ __forceinline__ float bfhi(unsigned int u) {
    return __uint_as_float(u & 0xffff0000u);
}

// ---------------- prep: fold query into layer-1 weights ----------------
__global__ void prep_kernel(const float* __restrict__ query,
                            const float* __restrict__ W0,
                            const float* __restrict__ b0,
                            float* __restrict__ blob, float* __restrict__ ws,
                            float* __restrict__ out) {
    const int b = blockIdx.x * 2 + (threadIdx.x >> 5);
    const int j = threadIdx.x & 31;
    if (blockIdx.x == 0) {
        for (int i = threadIdx.x; i < WS_ZERO_N; i += 64) ws[i] = 0.f;
    }
    if (j < DD) out[b * DD + j] = 0.f;
    float cj = b0[j];
    float* dst = blob + (size_t)b * BLOB_B + j * BLOB_J;
#pragma unroll
    for (int d = 0; d < DD; ++d) {
        float w_q = W0[d * C0 + j];
        float w_k = W0[(DD + d) * C0 + j];
        float w_d = W0[(2 * DD + d) * C0 + j];
        float w_p = W0[(3 * DD + d) * C0 + j];
        float qd = query[b * DD + d];
        dst[d] = w_k - w_d + qd * w_p;
        cj = fmaf(qd, w_q + w_d, cj);
    }
    dst[20] = cj;
}

// ================= finalize helpers =================
__device__ __forceinline__ void finalize0(int tid, float* __restrict__ ws,
                                          float2* __restrict__ lss0) {
    if (tid < C0) {
        float sv = 0.f, qv = 0.f;
#pragma unroll
        for (int k = 0; k < NSLOT; ++k) {
            sv += AGLOAD(&ws[WS_P1 + k * (2 * C0) + tid]);
            qv += AGLOAD(&ws[WS_P1 + k * (2 * C0) + C0 + tid]);
        }
        const float invN = 1.0f / (float)(BB * TT);
        float mean = sv * invN;
        float var = qv * invN - mean * mean;
        float sc = rsqrtf(var + 1e-9f);
        lss0[tid] = make_float2(sc, -mean * sc);
    }
}

__device__ __forceinline__ void finalize1(int tid, float* __restrict__ ws,
                                          const float* __restrict__ a1,
                                          const float* __restrict__ wk,
                                          float4* __restrict__ ld1v) {
    if (tid < C1) {
        float sv = 0.f, qv = 0.f;
#pragma unroll
        for (int k = 0; k < NSLOT; ++k) {
            sv += AGLOAD(&ws[WS_P2 + k * (2 * C1) + tid]);
            qv += AGLOAD(&ws[WS_P2 + k * (2 * C1) + C1 + tid]);
        }
        const float invN = 1.0f / (float)(BB * TT);
        float mean = sv * invN;
        float var = qv * invN - mean * mean;
        float sc = rsqrtf(var + 1e-9f);
        ld1v[tid] = make_float4(sc, -mean * sc, a1[tid], wk[tid]);
    }
}

// ---------------- pass A: layer-1 pre-acts + stats (+h0 cache) --------
template <bool WRITE>
__global__ __launch_bounds__(NTH, 2) void pass1_kernel(
    const float* __restrict__ keys, const float* __restrict__ blob,
    float* __restrict__ ws, unsigned int* __restrict__ h0c) {
    const int batch = blockIdx.x >> 2, part = blockIdx.x & 3;
    const int slot = blockIdx.x & (NSLOT - 1);
    const int tid = threadIdx.x, lane = tid & 63;
    const float* bA = blob + (size_t)batch * BLOB_B;
    const float* kbase = keys + ((size_t)batch * TT + part * CHUNK) * DD;

    float s[C0], q[C0];
#pragma unroll
    for (int j = 0; j < C0; ++j) { s[j] = 0.f; q[j] = 0.f; }

#pragma unroll 1
    for (int r = 0; r < CHUNK / NTH; ++r) {
        const int row = r * NTH + tid;
        float kk[DD];
        load_krow(kbase + (size_t)row * DD, kk);
#pragma unroll
        for (int d = 0; d < DD; ++d) PIN(kk[d]);
        const size_t pos = (size_t)batch * TT + part * CHUNK + row;
#pragma unroll
        for (int jg = 0; jg < 4; ++jg) {
            float h[8];
#pragma unroll
            for (int je = 0; je < 8; ++je) {
                const int j = jg * 8 + je;
                const float* wr = bA + j * BLOB_J;  // uniform -> s_load
                float hh = wr[20];
#pragma unroll
                for (int d = 0; d < DD; ++d) hh = fmaf(kk[d], wr[d], hh);
                h[je] = hh;
                s[j] += hh;
                q[j] = fmaf(hh, hh, q[j]);
            }
            if (WRITE) {
                uint4 u;
                u.x = pkbf(h[0], h[1]);
                u.y = pkbf(h[2], h[3]);
                u.z = pkbf(h[4], h[5]);
                u.w = pkbf(h[6], h[7]);
                *reinterpret_cast<uint4*>(h0c + pos * 16 + jg * 4) = u;
            }
        }
    }
    float redv = 0.f;
#pragma unroll
    for (int v = 0; v < 2 * C0; ++v) {
        float val = (v < C0) ? s[v] : q[v - C0];
#pragma unroll
        for (int o = 32; o >= 1; o >>= 1) val += __shfl_xor(val, o);
        if (lane == v) redv = val;
    }
    atomicAdd(&ws[WS_P1 + slot * (2 * C0) + lane], redv);
}

// ---------------- pass B: dice0 + layer-2 + stats (+v1 cache) ---------
template <bool CACHED>
__global__ __launch_bounds__(NTH, 2) void pass2_kernel(
    const float* __restrict__ keys, const float* __restrict__ blob,
    const float* __restrict__ a0, const float* __restrict__ W1,
    const float* __restrict__ b1, float* __restrict__ ws,
    const unsigned int* __restrict__ h0c, unsigned int* __restrict__ h1c) {
    const int batch = blockIdx.x >> 2, part = blockIdx.x & 3;
    const int slot = blockIdx.x & (NSLOT - 1);
    const int tid = threadIdx.x, lane = tid & 63;
    const float* bA = blob + (size_t)batch * BLOB_B;
    const float* kbase = keys + ((size_t)batch * TT + part * CHUNK) * DD;
    __shared__ float2 lss0[C0];
    finalize0(tid, ws, lss0);
    __syncthreads();

    float s1[C1], q1[C1];
#pragma unroll
    for (int c = 0; c < C1; ++c) { s1[c] = 0.f; q1[c] = 0.f; }

#pragma unroll 1
    for (int r = 0; r < CHUNK / NTH; ++r) {
        const int row = r * NTH + tid;
        const size_t pos = (size_t)batch * TT + part * CHUNK + row;
        float h1[C1];
#pragma unroll
        for (int c = 0; c < C1; ++c) h1[c] = 0.f;

        if (CACHED) {
            const uint4* hp =
                reinterpret_cast<const uint4*>(h0c + pos * 16);
            uint4 u0 = hp[0], u1 = hp[1], u2 = hp[2], u3 = hp[3];
            unsigned int uw[16] = {u0.x, u0.y, u0.z, u0.w, u1.x, u1.y,
                                   u1.z, u1.w, u2.x, u2.y, u2.z, u2.w,
                                   u3.x, u3.y, u3.z, u3.w};
#pragma unroll
            for (int jp = 0; jp < 16; ++jp) {
                const unsigned int u = uw[jp];
#pragma unroll
                for (int e = 0; e < 2; ++e) {
                    const int j = jp * 2 + e;
                    float hh = e ? bfhi(u) : bflo(u);
                    const float2 ss = lss0[j];
                    const float al = a0[j];
                    float pr = fast_sigmoid(fmaf(hh, ss.x, ss.y));
                    float gg = hh * fmaf(pr, 1.0f - al, al);
                    const float* ur = W1 + j * C1;
#pragma unroll
                    for (int c = 0; c < C1; ++c)
                        h1[c] = fmaf(gg, ur[c], h1[c]);
                }
            }
        } else {
            float kk[DD];
            load_krow(kbase + (size_t)row * DD, kk);
#pragma unroll
            for (int d = 0; d < DD; ++d) PIN(kk[d]);
#pragma unroll
            for (int j = 0; j < C0; ++j) {
                const float* wr = bA + j * BLOB_J;
                float hh = wr[20];
#pragma unroll
                for (int d = 0; d < DD; ++d) hh = fmaf(kk[d], wr[d], hh);
                const float2 ss = lss0[j];
                const float al = a0[j];
                float pr = fast_sigmoid(fmaf(hh, ss.x, ss.y));
                float gg = hh * fmaf(pr, 1.0f - al, al);
                const float* ur = W1 + j * C1;
#pragma unroll
                for (int c = 0; c < C1; ++c) h1[c] = fmaf(gg, ur[c], h1[c]);
            }
        }
        float vv[C1];
#pragma unroll
        for (int c = 0; c < C1; ++c) {
            vv[c] = h1[c] + b1[c];
            s1[c] += vv[c];
            q1[c] = fmaf(vv[c], vv[c], q1[c]);
        }
        if (CACHED) {
            uint4 w0, w1;
            w0.x = pkbf(vv[0], vv[1]);
            w0.y = pkbf(vv[2], vv[3]);
            w0.z = pkbf(vv[4], vv[5]);
            w0.w = pkbf(vv[6], vv[7]);
            w1.x = pkbf(vv[8], vv[9]);
            w1.y = pkbf(vv[10], vv[11]);
            w1.z = pkbf(vv[12], vv[13]);
            w1.w = pkbf(vv[14], vv[15]);
            uint4* wp = reinterpret_cast<uint4*>(h1c + pos * 8);
            wp[0] = w0;
            wp[1] = w1;
        }
    }
    float redv = 0.f;
#pragma unroll
    for (int v = 0; v < 2 * C1; ++v) {
        float val = (v < C1) ? s1[v] : q1[v - C1];
#pragma unroll
        for (int o = 32; o >= 1; o >>= 1) val += __shfl_xor(val, o);
        if (lane == v) redv = val;
    }
    if (lane < 2 * C1)
        atomicAdd(&ws[WS_P2 + slot * (2 * C1) + lane], redv);
}

// ---------------- pass C: dice1 + score + weighted key-sum ------------
template <bool CACHED>
__global__ __launch_bounds__(NTH, 2) void pass3_kernel(
    const float* __restrict__ keys, const float* __restrict__ blob,
    const float* __restrict__ a0, const float* __restrict__ W1,
    const float* __restrict__ b1, const float* __restrict__ a1,
    const float* __restrict__ wk, const float* __restrict__ bk,
    float* __restrict__ ws, float* __restrict__ out,
    const unsigned int* __restrict__ h1c) {
    const int batch = blockIdx.x >> 2, part = blockIdx.x & 3;
    const int tid = threadIdx.x, wave = tid >> 6, lane = tid & 63;
    const float* bA = blob + (size_t)batch * BLOB_B;
    const float* kbase = keys + ((size_t)batch * TT + part * CHUNK) * DD;
    __shared__ float2 lss0[C0];
    __shared__ float4 ld1v[C1];
    __shared__ float red[4][DD];
    if (!CACHED) finalize0(tid, ws, lss0);
    finalize1(tid, ws, a1, wk, ld1v);
    __syncthreads();

    const float bkv = bk[0];
    float oacc[DD];
#pragma unroll
    for (int d = 0; d < DD; ++d) oacc[d] = 0.f;

#pragma unroll 1
    for (int r = 0; r < CHUNK / NTH; ++r) {
        const int row = r * NTH + tid;
        const size_t pos = (size_t)batch * TT + part * CHUNK + row;
        float kk[DD];
        load_krow(kbase + (size_t)row * DD, kk);
#pragma unroll
        for (int d = 0; d < DD; ++d) PIN(kk[d]);
        float vv[C1];
        if (CACHED) {
            const uint4* hp = reinterpret_cast<const uint4*>(h1c + pos * 8);
            uint4 u0 = hp[0], u1 = hp[1];
            vv[0] = bflo(u0.x); vv[1] = bfhi(u0.x);
            vv[2] = bflo(u0.y); vv[3] = bfhi(u0.y);
            vv[4] = bflo(u0.z); vv[5] = bfhi(u0.z);
            vv[6] = bflo(u0.w); vv[7] = bfhi(u0.w);
            vv[8] = bflo(u1.x); vv[9] = bfhi(u1.x);
            vv[10] = bflo(u1.y); vv[11] = bfhi(u1.y);
            vv[12] = bflo(u1.z); vv[13] = bfhi(u1.z);
            vv[14] = bflo(u1.w); vv[15] = bfhi(u1.w);
        } else {
            float h1[C1];
#pragma unroll
            for (int c = 0; c < C1; ++c) h1[c] = 0.f;
#pragma unroll
            for (int j = 0; j < C0; ++j) {
                const float* wr = bA + j * BLOB_J;
                float hh = wr[20];
#pragma unroll
                for (int d = 0; d < DD; ++d) hh = fmaf(kk[d], wr[d], hh);
                const float2 ss = lss0[j];
                const float al = a0[j];
                float pr = fast_sigmoid(fmaf(hh, ss.x, ss.y));
                float gg = hh * fmaf(pr, 1.0f - al, al);
                const float* ur = W1 + j * C1;
#pragma unroll
                for (int c = 0; c < C1; ++c) h1[c] = fmaf(gg, ur[c], h1[c]);
            }
#pragma unroll
            for (int c = 0; c < C1; ++c) vv[c] = h1[c] + b1[c];
        }
        float score = bkv;
#pragma unroll
        for (int c = 0; c < C1; ++c) {
            float4 dv = ld1v[c];
            float pr = fast_sigmoid(fmaf(vv[c], dv.x, dv.y));
            float hd = vv[c] * fmaf(pr, 1.0f - dv.z, dv.z);
            score = fmaf(hd, dv.w, score);
        }
#pragma unroll
        for (int d = 0; d < DD; ++d) oacc[d] = fmaf(score, kk[d], oacc[d]);
    }
    float redv = 0.f;
#pragma unroll
    for (int v = 0; v < DD; ++v) {
        float val = oacc[v];
#pragma unroll
        for (int o = 32; o >= 1; o >>= 1) val += __shfl_xor(val, o);
        if (lane == v) redv = val;
    }
    if (lane < DD) red[wave][lane] = redv;
    __syncthreads();
    if (tid < DD)
        atomicAdd(&out[batch * DD + tid],
                  red[0][tid] + red[1][tid] + red[2][tid] + red[3][tid]);
}

extern "C" void kernel_launch(void* const* d_in, const int* in_sizes, int n_in,
                              void* d_out, int out_size, void* d_ws,
                              size_t ws_size, hipStream_t stream) {
    const float* keys = (const float*)d_in[0];
    const float* query = (const float*)d_in[1];
    // d_in[2] = mask: intentionally unused
    const float* W0 = (const float*)d_in[3];
    const float* b0 = (const float*)d_in[4];
    const float* a0 = (const float*)d_in[5];
    const float* W1 = (const float*)d_in[6];
    const float* b1 = (const float*)d_in[7];
    const float* a1 = (const float*)d_in[8];
    const float* wk = (const float*)d_in[9];
    const float* bk = (const float*)d_in[10];
    float* out = (float*)d_out;
    float* ws = (float*)d_ws;
    float* blob = ws + WS_BLOB;
    unsigned int* h0c = (unsigned int*)((char*)d_ws + H0_OFFB);
    unsigned int* h1c = (unsigned int*)((char*)d_ws + H1_OFFB);
    const bool cached = ws_size >= WS_NEED;

    prep_kernel<<<BB / 2, 64, 0, stream>>>(query, W0, b0, blob, ws, out);
    if (cached) {
        pass1_kernel<true><<<GRID, NTH, 0, stream>>>(keys, blob, ws, h0c);
        pass2_kernel<true><<<GRID, NTH, 0, stream>>>(keys, blob, a0, W1, b1,
                                                     ws, h0c, h1c);
        pass3_kernel<true><<<GRID, NTH, 0, stream>>>(keys, blob, a0, W1, b1,
                                                     a1, wk, bk, ws, out,
                                                     h1c);
    } else {
        pass1_kernel<false><<<GRID, NTH, 0, stream>>>(keys, blob, ws, h0c);
        pass2_kernel<false><<<GRID, NTH, 0, stream>>>(keys, blob, a0, W1, b1,
                                                      ws, h0c, h1c);
        pass3_kernel<false><<<GRID, NTH, 0, stream>>>(keys, blob, a0, W1, b1,
                                                      a1, wk, bk, ws, out,
                                                      h1c);
    }
}

// Round 9
// 293.228 us; speedup vs baseline: 1.2429x; 1.2429x over previous
//
#include <hip/hip_runtime.h>

// DIN attention unit, MI355X — round 15: R14 (MLP attack) made compilable.
// R14 failed on a preprocessor artifact: P##2.x pastes P with pp-number
// "2.x" -> invalid token. Fix: constant-indexed float4 arrays + inline
// functions (no token pasting; const-indexed arrays stay in registers).
// Theory unchanged: all kernels ran at hbm_bytes/~650GB/s = MLP-limited
// (~7 waves/CU x ~160B in flight). Fix: (a) grid 1024 = 4 blocks/CU with
// VGPR<=128 under (256,2); (b) 2-deep per-thread register load queue,
// fully unrolled 4 rows/thread, loads issued ahead of each row's 640-FMA
// compute; PIN at consumption. fp32 recompute math (R11-proven).
// Weights on scalar path; AGENT-scope stat readback (R9 fix).
// mask input UNUSED (reference uses unmasked scores — reproduced bug).

#define BB 512
#define TT 2048
#define DD 20
#define C0 32
#define C1 16

#define NTH 256              // 4 waves/block
#define CHUNK 1024           // rows per block (4 rows/thread)
#define NBLK (TT / CHUNK)    // 2 blocks per batch
#define GRID (BB * NBLK)     // 1024 blocks = 4 per CU
#define NSLOT 8              // atomic slot-split

// ws float offsets
#define WS_P1 0              // 8 slots * (32 sum + 32 sq)
#define WS_P2 512            // 8 slots * (16 sum + 16 sq)
#define WS_ZERO_N 768
#define WS_BLOB 896
#define BLOB_J 24            // 20 wM + c + pad
#define BLOB_B (C0 * BLOB_J)

#define PIN(x) asm volatile("" : "+v"(x))
#define AGLOAD(p) \
    __hip_atomic_load((p), __ATOMIC_RELAXED, __HIP_MEMORY_SCOPE_AGENT)

__device__ __forceinline__ float fast_sigmoid(float x) {
    return __builtin_amdgcn_rcpf(1.0f + __expf(-x));
}

// Issue 5 float4 loads for one 80B key row into a register slot.
__device__ __forceinline__ void load5(const float* __restrict__ row,
                                      float4 (&P)[5]) {
    const float4* k4 = (const float4*)row;  // rows are 80B => 16B aligned
    P[0] = k4[0];
    P[1] = k4[1];
    P[2] = k4[2];
    P[3] = k4[3];
    P[4] = k4[4];
}

// Unpack slot to scalars; PIN at consumption (vmcnt wait lands here, other
// slots' loads stay in flight).
__device__ __forceinline__ void unpack20(const float4 (&P)[5],
                                         float (&kk)[DD]) {
#pragma unroll
    for (int u = 0; u < 5; ++u) {
        kk[u * 4 + 0] = P[u].x;
        kk[u * 4 + 1] = P[u].y;
        kk[u * 4 + 2] = P[u].z;
        kk[u * 4 + 3] = P[u].w;
    }
#pragma unroll
    for (int d = 0; d < DD; ++d) PIN(kk[d]);
}

// ---------------- prep: fold query into layer-1 weights ----------------
__global__ void prep_kernel(const float* __restrict__ query,
                            const float* __restrict__ W0,
                            const float* __restrict__ b0,
                            float* __restrict__ blob, float* __restrict__ ws,
                            float* __restrict__ out) {
    const int b = blockIdx.x * 2 + (threadIdx.x >> 5);
    const int j = threadIdx.x & 31;
    if (blockIdx.x == 0) {
        for (int i = threadIdx.x; i < WS_ZERO_N; i += 64) ws[i] = 0.f;
    }
    if (j < DD) out[b * DD + j] = 0.f;
    float cj = b0[j];
    float* dst = blob + (size_t)b * BLOB_B + j * BLOB_J;
#pragma unroll
    for (int d = 0; d < DD; ++d) {
        float w_q = W0[d * C0 + j];
        float w_k = W0[(DD + d) * C0 + j];
        float w_d = W0[(2 * DD + d) * C0 + j];
        float w_p = W0[(3 * DD + d) * C0 + j];
        float qd = query[b * DD + d];
        dst[d] = w_k - w_d + qd * w_p;
        cj = fmaf(qd, w_q + w_d, cj);
    }
    dst[20] = cj;
}

// ================= finalize helpers =================
__device__ __forceinline__ void finalize0(int tid, float* __restrict__ ws,
                                          float2* __restrict__ lss0) {
    if (tid < C0) {
        float sv = 0.f, qv = 0.f;
#pragma unroll
        for (int k = 0; k < NSLOT; ++k) {
            sv += AGLOAD(&ws[WS_P1 + k * (2 * C0) + tid]);
            qv += AGLOAD(&ws[WS_P1 + k * (2 * C0) + C0 + tid]);
        }
        const float invN = 1.0f / (float)(BB * TT);
        float mean = sv * invN;
        float var = qv * invN - mean * mean;
        float sc = rsqrtf(var + 1e-9f);
        lss0[tid] = make_float2(sc, -mean * sc);
    }
}

__device__ __forceinline__ void finalize1(int tid, float* __restrict__ ws,
                                          const float* __restrict__ a1,
                                          const float* __restrict__ wk,
                                          float4* __restrict__ ld1v) {
    if (tid < C1) {
        float sv = 0.f, qv = 0.f;
#pragma unroll
        for (int k = 0; k < NSLOT; ++k) {
            sv += AGLOAD(&ws[WS_P2 + k * (2 * C1) + tid]);
            qv += AGLOAD(&ws[WS_P2 + k * (2 * C1) + C1 + tid]);
        }
        const float invN = 1.0f / (float)(BB * TT);
        float mean = sv * invN;
        float var = qv * invN - mean * mean;
        float sc = rsqrtf(var + 1e-9f);
        ld1v[tid] = make_float4(sc, -mean * sc, a1[tid], wk[tid]);
    }
}

// ---------------- pass 1: layer-1 pre-activation stats ----------------
__device__ __forceinline__ void p1row(const float4 (&P)[5],
                                      const float* __restrict__ bA,
                                      float (&s)[C0], float (&q)[C0]) {
    float kk[DD];
    unpack20(P, kk);
#pragma unroll
    for (int j = 0; j < C0; ++j) {
        const float* wr = bA + j * BLOB_J;  // uniform -> s_load
        float hh = wr[20];
#pragma unroll
        for (int d = 0; d < DD; ++d) hh = fmaf(kk[d], wr[d], hh);
        s[j] += hh;
        q[j] = fmaf(hh, hh, q[j]);
    }
}

__global__ __launch_bounds__(NTH, 2) void pass1_kernel(
    const float* __restrict__ keys, const float* __restrict__ blob,
    float* __restrict__ ws) {
    const int batch = blockIdx.x >> 1, chunk = blockIdx.x & 1;
    const int slot = blockIdx.x & (NSLOT - 1);
    const int tid = threadIdx.x, lane = tid & 63;
    const float* bA = blob + (size_t)batch * BLOB_B;
    const float* kbase = keys + ((size_t)batch * TT + chunk * CHUNK) * DD;

    float s[C0], q[C0];
#pragma unroll
    for (int j = 0; j < C0; ++j) { s[j] = 0.f; q[j] = 0.f; }

    // 4 rows/thread, 2-deep register queue, fully unrolled
    float4 A[5], B[5];
    load5(kbase + (size_t)tid * DD, A);
    load5(kbase + (size_t)(tid + NTH) * DD, B);
    p1row(A, bA, s, q);
    load5(kbase + (size_t)(tid + 2 * NTH) * DD, A);
    p1row(B, bA, s, q);
    load5(kbase + (size_t)(tid + 3 * NTH) * DD, B);
    p1row(A, bA, s, q);
    p1row(B, bA, s, q);

    float redv = 0.f;
#pragma unroll
    for (int v = 0; v < 2 * C0; ++v) {
        float val = (v < C0) ? s[v] : q[v - C0];
#pragma unroll
        for (int o = 32; o >= 1; o >>= 1) val += __shfl_xor(val, o);
        if (lane == v) redv = val;
    }
    atomicAdd(&ws[WS_P1 + slot * (2 * C0) + lane], redv);
}

// ---------------- pass 2: layer-2 pre-activation stats ----------------
__device__ __forceinline__ void p2row(const float4 (&P)[5],
                                      const float* __restrict__ bA,
                                      const float* __restrict__ a0,
                                      const float* __restrict__ W1,
                                      const float* __restrict__ b1,
                                      const float2* __restrict__ lss0,
                                      float (&s1)[C1], float (&q1)[C1]) {
    float kk[DD];
    unpack20(P, kk);
    float h1[C1];
#pragma unroll
    for (int c = 0; c < C1; ++c) h1[c] = 0.f;
#pragma unroll
    for (int j = 0; j < C0; ++j) {
        const float* wr = bA + j * BLOB_J;
        float hh = wr[20];
#pragma unroll
        for (int d = 0; d < DD; ++d) hh = fmaf(kk[d], wr[d], hh);
        const float2 ss = lss0[j];
        const float al = a0[j];
        float pr = fast_sigmoid(fmaf(hh, ss.x, ss.y));
        float gg = hh * fmaf(pr, 1.0f - al, al);
        const float* ur = W1 + j * C1;
#pragma unroll
        for (int c = 0; c < C1; ++c) h1[c] = fmaf(gg, ur[c], h1[c]);
    }
#pragma unroll
    for (int c = 0; c < C1; ++c) {
        float v = h1[c] + b1[c];
        s1[c] += v;
        q1[c] = fmaf(v, v, q1[c]);
    }
}

__global__ __launch_bounds__(NTH, 2) void pass2_kernel(
    const float* __restrict__ keys, const float* __restrict__ blob,
    const float* __restrict__ a0, const float* __restrict__ W1,
    const float* __restrict__ b1, float* __restrict__ ws) {
    const int batch = blockIdx.x >> 1, chunk = blockIdx.x & 1;
    const int slot = blockIdx.x & (NSLOT - 1);
    const int tid = threadIdx.x, lane = tid & 63;
    const float* bA = blob + (size_t)batch * BLOB_B;
    const float* kbase = keys + ((size_t)batch * TT + chunk * CHUNK) * DD;
    __shared__ float2 lss0[C0];
    finalize0(tid, ws, lss0);
    __syncthreads();

    float s1[C1], q1[C1];
#pragma unroll
    for (int c = 0; c < C1; ++c) { s1[c] = 0.f; q1[c] = 0.f; }

    float4 A[5], B[5];
    load5(kbase + (size_t)tid * DD, A);
    load5(kbase + (size_t)(tid + NTH) * DD, B);
    p2row(A, bA, a0, W1, b1, lss0, s1, q1);
    load5(kbase + (size_t)(tid + 2 * NTH) * DD, A);
    p2row(B, bA, a0, W1, b1, lss0, s1, q1);
    load5(kbase + (size_t)(tid + 3 * NTH) * DD, B);
    p2row(A, bA, a0, W1, b1, lss0, s1, q1);
    p2row(B, bA, a0, W1, b1, lss0, s1, q1);

    float redv = 0.f;
#pragma unroll
    for (int v = 0; v < 2 * C1; ++v) {
        float val = (v < C1) ? s1[v] : q1[v - C1];
#pragma unroll
        for (int o = 32; o >= 1; o >>= 1) val += __shfl_xor(val, o);
        if (lane == v) redv = val;
    }
    if (lane < 2 * C1)
        atomicAdd(&ws[WS_P2 + slot * (2 * C1) + lane], redv);
}

// ---------------- pass 3: full tower + weighted key-sum ----------------
__device__ __forceinline__ void p3row(
    const float4 (&P)[5], const float* __restrict__ bA,
    const float* __restrict__ a0, const float* __restrict__ W1,
    const float* __restrict__ b1, const float2* __restrict__ lss0,
    const float4* __restrict__ ld1v, float bkv, float (&oacc)[DD]) {
    float kk[DD];
    unpack20(P, kk);
    float h1[C1];
#pragma unroll
    for (int c = 0; c < C1; ++c) h1[c] = 0.f;
#pragma unroll
    for (int j = 0; j < C0; ++j) {
        const float* wr = bA + j * BLOB_J;
        float hh = wr[20];
#pragma unroll
        for (int d = 0; d < DD; ++d) hh = fmaf(kk[d], wr[d], hh);
        const float2 ss = lss0[j];
        const float al = a0[j];
        float pr = fast_sigmoid(fmaf(hh, ss.x, ss.y));
        float gg = hh * fmaf(pr, 1.0f - al, al);
        const float* ur = W1 + j * C1;
#pragma unroll
        for (int c = 0; c < C1; ++c) h1[c] = fmaf(gg, ur[c], h1[c]);
    }
    float score = bkv;
#pragma unroll
    for (int c = 0; c < C1; ++c) {
        float v = h1[c] + b1[c];
        float4 dv = ld1v[c];
        float pr = fast_sigmoid(fmaf(v, dv.x, dv.y));
        float hd = v * fmaf(pr, 1.0f - dv.z, dv.z);
        score = fmaf(hd, dv.w, score);
    }
#pragma unroll
    for (int d = 0; d < DD; ++d) oacc[d] = fmaf(score, kk[d], oacc[d]);
}

__global__ __launch_bounds__(NTH, 2) void pass3_kernel(
    const float* __restrict__ keys, const float* __restrict__ blob,
    const float* __restrict__ a0, const float* __restrict__ W1,
    const float* __restrict__ b1, const float* __restrict__ a1,
    const float* __restrict__ wk, const float* __restrict__ bk,
    float* __restrict__ ws, float* __restrict__ out) {
    const int batch = blockIdx.x >> 1, chunk = blockIdx.x & 1;
    const int tid = threadIdx.x, wave = tid >> 6, lane = tid & 63;
    const float* bA = blob + (size_t)batch * BLOB_B;
    const float* kbase = keys + ((size_t)batch * TT + chunk * CHUNK) * DD;
    __shared__ float2 lss0[C0];
    __shared__ float4 ld1v[C1];
    __shared__ float red[4][DD];
    finalize0(tid, ws, lss0);
    finalize1(tid, ws, a1, wk, ld1v);
    __syncthreads();

    const float bkv = bk[0];
    float oacc[DD];
#pragma unroll
    for (int d = 0; d < DD; ++d) oacc[d] = 0.f;

    float4 A[5], B[5];
    load5(kbase + (size_t)tid * DD, A);
    load5(kbase + (size_t)(tid + NTH) * DD, B);
    p3row(A, bA, a0, W1, b1, lss0, ld1v, bkv, oacc);
    load5(kbase + (size_t)(tid + 2 * NTH) * DD, A);
    p3row(B, bA, a0, W1, b1, lss0, ld1v, bkv, oacc);
    load5(kbase + (size_t)(tid + 3 * NTH) * DD, B);
    p3row(A, bA, a0, W1, b1, lss0, ld1v, bkv, oacc);
    p3row(B, bA, a0, W1, b1, lss0, ld1v, bkv, oacc);

    float redv = 0.f;
#pragma unroll
    for (int v = 0; v < DD; ++v) {
        float val = oacc[v];
#pragma unroll
        for (int o = 32; o >= 1; o >>= 1) val += __shfl_xor(val, o);
        if (lane == v) redv = val;
    }
    if (lane < DD) red[wave][lane] = redv;
    __syncthreads();
    if (tid < DD)
        atomicAdd(&out[batch * DD + tid],
                  red[0][tid] + red[1][tid] + red[2][tid] + red[3][tid]);
}

extern "C" void kernel_launch(void* const* d_in, const int* in_sizes, int n_in,
                              void* d_out, int out_size, void* d_ws,
                              size_t ws_size, hipStream_t stream) {
    const float* keys = (const float*)d_in[0];
    const float* query = (const float*)d_in[1];
    // d_in[2] = mask: intentionally unused
    const float* W0 = (const float*)d_in[3];
    const float* b0 = (const float*)d_in[4];
    const float* a0 = (const float*)d_in[5];
    const float* W1 = (const float*)d_in[6];
    const float* b1 = (const float*)d_in[7];
    const float* a1 = (const float*)d_in[8];
    const float* wk = (const float*)d_in[9];
    const float* bk = (const float*)d_in[10];
    float* out = (float*)d_out;
    float* ws = (float*)d_ws;
    float* blob = ws + WS_BLOB;

    prep_kernel<<<BB / 2, 64, 0, stream>>>(query, W0, b0, blob, ws, out);
    pass1_kernel<<<GRID, NTH, 0, stream>>>(keys, blob, ws);
    pass2_kernel<<<GRID, NTH, 0, stream>>>(keys, blob, a0, W1, b1, ws);
    pass3_kernel<<<GRID, NTH, 0, stream>>>(keys, blob, a0, W1, b1, a1, wk,
                                           bk, ws, out);
}